// Round 7
// baseline (507.205 us; speedup 1.0000x reference)
//
#include <hip/hip_runtime.h>
#include <math.h>

#define B_  4
#define L_  1024
#define DM  1024
#define DI  1024
#define DS  16
#define DR  64
#define DCV 4
#define NH  4
#define DK  256

#define NCH 32         // scan time-chunks
#define CHL (L_ / NCH) // 32 steps per chunk

typedef __attribute__((ext_vector_type(8))) short short8;
typedef __attribute__((ext_vector_type(4))) float floatx4;

static __device__ __forceinline__ unsigned short f2bf(float f) {
    unsigned int u = __float_as_uint(f);
    u += 0x7fffu + ((u >> 16) & 1u);
    return (unsigned short)(u >> 16);
}
static __device__ __forceinline__ float bf2f(unsigned short s) {
    return __uint_as_float(((unsigned int)s) << 16);
}

// ---------------------------------------------------------------------------
// Fused fp32->bf16 casts
// ---------------------------------------------------------------------------
struct CastArgs {
    const float* s[8];
    unsigned short* d[8];
    int n[8];
    int ns[8];
};

__global__ __launch_bounds__(256) void cast_multi(CastArgs ca)
{
    int y = blockIdx.y;
    int i = (blockIdx.x * 256 + threadIdx.x) * 4;
    if (i >= ca.n[y]) return;
    const float* s = ca.s[y];
    unsigned short* d = ca.d[y];
    int ns = ca.ns[y];
    ushort4 o;
    if (i + 4 <= ns) {
        float4 v = *(const float4*)(s + i);
        o.x = f2bf(v.x); o.y = f2bf(v.y); o.z = f2bf(v.z); o.w = f2bf(v.w);
    } else {
        float v[4];
#pragma unroll
        for (int j = 0; j < 4; j++) v[j] = (i + j < ns) ? s[i + j] : 0.f;
        o.x = f2bf(v[0]); o.y = f2bf(v[1]); o.z = f2bf(v[2]); o.w = f2bf(v[3]);
    }
    *(ushort4*)(d + i) = o;
}

// ---------------------------------------------------------------------------
// Multi-descriptor bf16 MFMA GEMM: per z, C = act(A @ W^T * scale + bias)
// mode & 3: 0 = fp32 out, 1 = bf16 out, 2 = both. mode & 4: softplus.
// ---------------------------------------------------------------------------
struct GDesc {
    const unsigned short* A;
    const unsigned short* W;
    const float* bias;
    float* Cf;
    unsigned short* Cb;
    int K, lda, ldw, ldc, ldc2;
    int mode;
    float scale;
    int gx, gy;
};
struct GArgs { GDesc g[3]; };

__global__ __launch_bounds__(256) void gemm_multi(GArgs ga)
{
    GDesc g = ga.g[blockIdx.z];
    if ((int)blockIdx.x >= g.gx || (int)blockIdx.y >= g.gy) return;

    __shared__ __align__(16) unsigned short Asm[128 * 32];
    __shared__ __align__(16) unsigned short Bsm[128 * 32];

    int tid = threadIdx.x;
    int wid = tid >> 6;
    int lane = tid & 63;
    int wm = wid & 1, wn = wid >> 1;
    int lr = lane & 15, quad = lane >> 4;

    const unsigned short* Ab = g.A + (size_t)blockIdx.y * 128 * g.lda;
    const unsigned short* Wb = g.W + (size_t)blockIdx.x * 128 * g.ldw;

    int srow = tid >> 2;
    int scol = (tid & 3) * 8;
    const unsigned short* Ap = Ab + (size_t)srow * g.lda + scol;
    const unsigned short* Wp = Wb + (size_t)srow * g.ldw + scol;

    unsigned short* lA0 = &Asm[(wid * 16) * 32];
    unsigned short* lA1 = &Asm[(64 + wid * 16) * 32];
    unsigned short* lB0 = &Bsm[(wid * 16) * 32];
    unsigned short* lB1 = &Bsm[(64 + wid * 16) * 32];

    floatx4 acc[4][4];
#pragma unroll
    for (int i = 0; i < 4; i++)
#pragma unroll
        for (int j = 0; j < 4; j++) acc[i][j] = (floatx4){0.f, 0.f, 0.f, 0.f};

#define GLL(gp, lp) __builtin_amdgcn_global_load_lds( \
        (const __attribute__((address_space(1))) void*)(gp), \
        (__attribute__((address_space(3))) void*)(lp), 16, 0, 0)

    for (int k0 = 0; k0 < g.K; k0 += 32) {
        GLL(Ap, lA0);
        GLL(Ap + (size_t)64 * g.lda, lA1);
        GLL(Wp, lB0);
        GLL(Wp + (size_t)64 * g.ldw, lB1);
        Ap += 32; Wp += 32;
        __syncthreads();

        short8 af[4], bf[4];
#pragma unroll
        for (int mt = 0; mt < 4; mt++)
            af[mt] = *(const short8*)&Asm[(wm * 64 + mt * 16 + lr) * 32 + quad * 8];
#pragma unroll
        for (int nt = 0; nt < 4; nt++)
            bf[nt] = *(const short8*)&Bsm[(wn * 64 + nt * 16 + lr) * 32 + quad * 8];
#pragma unroll
        for (int mt = 0; mt < 4; mt++)
#pragma unroll
            for (int nt = 0; nt < 4; nt++)
                acc[mt][nt] = __builtin_amdgcn_mfma_f32_16x16x32_bf16(
                    af[mt], bf[nt], acc[mt][nt], 0, 0, 0);
        __syncthreads();
    }
#undef GLL

    int bm = blockIdx.y * 128, bn = blockIdx.x * 128;
    int m = g.mode & 3;
#pragma unroll
    for (int mt = 0; mt < 4; mt++) {
#pragma unroll
        for (int nt = 0; nt < 4; nt++) {
            int row0 = bm + wm * 64 + mt * 16 + quad * 4;
            int col = bn + wn * 64 + nt * 16 + lr;
            float bv = g.bias ? g.bias[col] : 0.f;
#pragma unroll
            for (int i = 0; i < 4; i++) {
                float v = acc[mt][nt][i] * g.scale + bv;
                if (g.mode & 4) v = (v > 15.f) ? v : log1pf(__expf(v));
                if (m == 0) {
                    g.Cf[(size_t)(row0 + i) * g.ldc + col] = v;
                } else if (m == 1) {
                    g.Cb[(size_t)(row0 + i) * g.ldc + col] = f2bf(v);
                } else {
                    g.Cf[(size_t)(row0 + i) * g.ldc + col] = v;
                    g.Cb[(size_t)(row0 + i) * g.ldc2 + col] = f2bf(v);
                }
            }
        }
    }
}

// ---------------------------------------------------------------------------
// Flash attention v3: barrier-free + split-K2.
// Grid 512 1D: bh = id&15 (XCD-local L2 residency for K/Q/VT), qt = (id>>4)&15,
// sk = id>>8 selects key half [sk*512, sk*512+512).
// 4 waves x 16 q-rows, NO __syncthreads anywhere: K fragments read directly
// from global (L2), P round-trips through a per-wave LDS region, V fragments
// in a single register buffer loaded in two halves.
// Emits unnormalized fp32 partial O + per-row (m, l); merged by attn_merge.
// ---------------------------------------------------------------------------
__global__ __launch_bounds__(256, 2) void flash_attn(
    const unsigned short* __restrict__ Q, const unsigned short* __restrict__ Kg,
    const unsigned short* __restrict__ VT, float* __restrict__ Opart,
    float* __restrict__ mbuf, float* __restrict__ lbuf)
{
    __shared__ __align__(16) unsigned short Pp[4 * 16 * 72];  // 9 KB

    int id = blockIdx.x;
    int bh = id & 15;
    int qt = (id >> 4) & 15;
    int sk = id >> 8;
    int b = bh >> 2, h = bh & 3;
    int q0 = qt * 64;
    int tid = threadIdx.x;
    int wid = tid >> 6, lane = tid & 63;
    int lr = lane & 15, quad = lane >> 4;
    const float scale = 0.0625f;   // 1/sqrt(256)

    // Q fragments: rows q0 + wid*16 + lr, all 256 dims
    short8 qf[8];
    const unsigned short* qbase = Q + ((size_t)(b * L_ + q0 + wid * 16 + lr)) * 1024 + h * DK;
#pragma unroll
    for (int kf = 0; kf < 8; kf++)
        qf[kf] = *(const short8*)(qbase + kf * 32 + quad * 8);

    floatx4 o_acc[16];
#pragma unroll
    for (int i = 0; i < 16; i++) o_acc[i] = (floatx4){0.f, 0.f, 0.f, 0.f};
    float m_i[4] = {-3e38f, -3e38f, -3e38f, -3e38f};
    float l_i[4] = {0.f, 0.f, 0.f, 0.f};

    unsigned short* pw = &Pp[wid * 16 * 72];
    const unsigned short* vbase = VT + ((size_t)bh * DK + lr) * 1024 + quad * 8;
    const unsigned short* kbase = Kg + ((size_t)(b * L_) + lr) * 1024 + h * DK + quad * 8;

    for (int kt = 0; kt < 8; kt++) {
        int k0 = sk * 512 + kt * 64;

        // prefetch V fragments, first half (keys k0 .. k0+31)
        short8 vf[16];
#pragma unroll
        for (int ntd = 0; ntd < 16; ntd++)
            vf[ntd] = *(const short8*)(vbase + (size_t)ntd * 16 * 1024 + k0);

        // S = Q K^T  — K fragments straight from global (L2-resident)
        floatx4 sacc[4];
#pragma unroll
        for (int nt = 0; nt < 4; nt++) sacc[nt] = (floatx4){0.f, 0.f, 0.f, 0.f};
#pragma unroll
        for (int kf = 0; kf < 8; kf++) {
#pragma unroll
            for (int nt = 0; nt < 4; nt++) {
                short8 kfr = *(const short8*)(kbase + (size_t)(k0 + nt * 16) * 1024 + kf * 32);
                sacc[nt] = __builtin_amdgcn_mfma_f32_16x16x32_bf16(qf[kf], kfr, sacc[nt], 0, 0, 0);
            }
        }

        // online softmax update (rows quad*4+i, cols nt*16+lr)
        float p_[4][4];
        float al[4];
#pragma unroll
        for (int i = 0; i < 4; i++) {
            float tm = sacc[0][i];
            tm = fmaxf(tm, sacc[1][i]);
            tm = fmaxf(tm, sacc[2][i]);
            tm = fmaxf(tm, sacc[3][i]);
            tm *= scale;
            tm = fmaxf(tm, __shfl_xor(tm, 1));
            tm = fmaxf(tm, __shfl_xor(tm, 2));
            tm = fmaxf(tm, __shfl_xor(tm, 4));
            tm = fmaxf(tm, __shfl_xor(tm, 8));
            float mn = fmaxf(m_i[i], tm);
            al[i] = __expf(m_i[i] - mn);
            m_i[i] = mn;
            float ts = 0.f;
#pragma unroll
            for (int nt = 0; nt < 4; nt++) {
                float pv = __expf(sacc[nt][i] * scale - mn);
                p_[nt][i] = pv;
                ts += pv;
            }
            ts += __shfl_xor(ts, 1);
            ts += __shfl_xor(ts, 2);
            ts += __shfl_xor(ts, 4);
            ts += __shfl_xor(ts, 8);
            l_i[i] = al[i] * l_i[i] + ts;
        }

        // write P (bf16) to per-wave LDS region (C-layout -> A-layout)
#pragma unroll
        for (int nt = 0; nt < 4; nt++)
#pragma unroll
            for (int i = 0; i < 4; i++)
                pw[(quad * 4 + i) * 72 + nt * 16 + lr] = f2bf(p_[nt][i]);

        // rescale O
#pragma unroll
        for (int ntd = 0; ntd < 16; ntd++) {
            floatx4 t = o_acc[ntd];
            t[0] *= al[0]; t[1] *= al[1]; t[2] *= al[2]; t[3] *= al[3];
            o_acc[ntd] = t;
        }

        short8 pf0 = *(const short8*)&pw[lr * 72 + quad * 8];
        short8 pf1 = *(const short8*)&pw[lr * 72 + 32 + quad * 8];

        // O += P0 @ V0 (first key half, prefetched)
#pragma unroll
        for (int ntd = 0; ntd < 16; ntd++)
            o_acc[ntd] = __builtin_amdgcn_mfma_f32_16x16x32_bf16(pf0, vf[ntd], o_acc[ntd], 0, 0, 0);

        // load V second half, then O += P1 @ V1
#pragma unroll
        for (int ntd = 0; ntd < 16; ntd++)
            vf[ntd] = *(const short8*)(vbase + (size_t)ntd * 16 * 1024 + k0 + 32);
#pragma unroll
        for (int ntd = 0; ntd < 16; ntd++)
            o_acc[ntd] = __builtin_amdgcn_mfma_f32_16x16x32_bf16(pf1, vf[ntd], o_acc[ntd], 0, 0, 0);
    }

    // epilogue: store UNNORMALIZED fp32 partial + (m, l)
    float* ob = Opart + (size_t)sk * 4194304
              + ((size_t)(b * L_ + q0 + wid * 16 + quad * 4)) * 1024 + h * DK + lr;
#pragma unroll
    for (int ntd = 0; ntd < 16; ntd++)
#pragma unroll
        for (int i = 0; i < 4; i++)
            ob[(size_t)i * 1024 + ntd * 16] = o_acc[ntd][i];

    if (lr == 0) {
        int row = q0 + wid * 16 + quad * 4;
#pragma unroll
        for (int i = 0; i < 4; i++) {
            mbuf[sk * 16384 + bh * 1024 + row + i] = m_i[i];
            lbuf[sk * 16384 + bh * 1024 + row + i] = l_i[i];
        }
    }
}

// ---------------------------------------------------------------------------
// Merge the two split-K partials -> AO bf16
// ---------------------------------------------------------------------------
__global__ __launch_bounds__(256) void attn_merge(
    const float* __restrict__ Opart, const float* __restrict__ mbuf,
    const float* __restrict__ lbuf, unsigned short* __restrict__ AO)
{
    int gid = blockIdx.x * 256 + threadIdx.x;   // over 4096*256
    int row = gid >> 8;            // 0..4095  (b*1024 + l)
    int c4 = (gid & 255) * 4;      // col
    int b = row >> 10, l = row & 1023;
    int bh = b * 4 + (c4 >> 8);
    int mo = bh * 1024 + l;

    float m0 = mbuf[mo], l0 = lbuf[mo];
    float m1 = mbuf[16384 + mo], l1 = lbuf[16384 + mo];
    float M = fmaxf(m0, m1);
    float w0 = __expf(m0 - M), w1 = __expf(m1 - M);
    float inv = 1.0f / (w0 * l0 + w1 * l1);

    size_t o = (size_t)row * 1024 + c4;
    float4 a0 = *(const float4*)(Opart + o);
    float4 a1 = *(const float4*)(Opart + 4194304 + o);
    ushort4 r;
    r.x = f2bf((w0 * a0.x + w1 * a1.x) * inv);
    r.y = f2bf((w0 * a0.y + w1 * a1.y) * inv);
    r.z = f2bf((w0 * a0.z + w1 * a1.z) * inv);
    r.w = f2bf((w0 * a0.w + w1 * a1.w) * inv);
    *(ushort4*)(AO + o) = r;
}

// ---------------------------------------------------------------------------
// Depthwise causal conv1d + bias + SiLU; writes fp32 u and bf16 u
// ---------------------------------------------------------------------------
__global__ __launch_bounds__(256) void conv_silu_kernel(
    const float* __restrict__ xx, const float* __restrict__ cw,
    const float* __restrict__ cb, float* __restrict__ u,
    unsigned short* __restrict__ ub)
{
    int idx = blockIdx.x * 256 + threadIdx.x;
    int d = idx & (DI - 1);
    int l = (idx >> 10) & (L_ - 1);
    int b = idx >> 20;
    const float* xb = xx + (size_t)b * L_ * DI + d;
    float z = cb[d];
#pragma unroll
    for (int j = 0; j < DCV; j++) {
        int t = l - (DCV - 1) + j;
        if (t >= 0) z += xb[(size_t)t * DI] * cw[d * DCV + j];
    }
    float v = z / (1.0f + __expf(-z));
    u[idx] = v;
    ub[idx] = f2bf(v);
}

// ---------------------------------------------------------------------------
// Scan phase A
// ---------------------------------------------------------------------------
__global__ __launch_bounds__(256) void scan_a(
    const float* __restrict__ delta, const float* __restrict__ u,
    const float* __restrict__ xdbl, const float* __restrict__ A_log,
    float* __restrict__ Hc, float* __restrict__ sumdv)
{
    int gid = blockIdx.x * 256 + threadIdx.x;
    int c = gid >> 12;
    int bd = gid & 4095;
    int b = bd >> 10, d = bd & 1023;

    float a[16];
#pragma unroll
    for (int j = 0; j < 4; j++) {
        float4 al = *(const float4*)(A_log + d * 16 + j * 4);
        a[j * 4 + 0] = -__expf(al.x); a[j * 4 + 1] = -__expf(al.y);
        a[j * 4 + 2] = -__expf(al.z); a[j * 4 + 3] = -__expf(al.w);
    }
    float h[16];
#pragma unroll
    for (int n = 0; n < 16; n++) h[n] = 0.f;
    float sd = 0.f;

    int t0 = c * CHL;
    const float* dp = delta + ((size_t)(b * L_) + t0) * DI + d;
    const float* up = u + ((size_t)(b * L_) + t0) * DI + d;
    const float* xp = xdbl + ((size_t)(b * L_) + t0) * 128;

#pragma unroll 4
    for (int t = 0; t < CHL; t++) {
        float dv = dp[t * DI];
        float uv = up[t * DI];
        float duv = dv * uv;
        sd += dv;
        float Bv[16];
#pragma unroll
        for (int j = 0; j < 4; j++) {
            float4 bq = *(const float4*)(xp + t * 128 + 64 + j * 4);
            Bv[j * 4 + 0] = bq.x; Bv[j * 4 + 1] = bq.y;
            Bv[j * 4 + 2] = bq.z; Bv[j * 4 + 3] = bq.w;
        }
#pragma unroll
        for (int n = 0; n < 16; n++)
            h[n] = __expf(dv * a[n]) * h[n] + duv * Bv[n];
    }

    float* hp = Hc + ((size_t)c * 4096 + bd) * 16;
#pragma unroll
    for (int j = 0; j < 4; j++)
        *(float4*)(hp + j * 4) = make_float4(h[j * 4], h[j * 4 + 1], h[j * 4 + 2], h[j * 4 + 3]);
    sumdv[c * 4096 + bd] = sd;
}

// ---------------------------------------------------------------------------
// Scan phase B
// ---------------------------------------------------------------------------
__global__ __launch_bounds__(256) void scan_b(
    float* __restrict__ Hc, const float* __restrict__ sumdv,
    const float* __restrict__ A_log)
{
    int bd = blockIdx.x * 256 + threadIdx.x;
    int d = bd & 1023;

    float a[16];
#pragma unroll
    for (int j = 0; j < 4; j++) {
        float4 al = *(const float4*)(A_log + d * 16 + j * 4);
        a[j * 4 + 0] = -__expf(al.x); a[j * 4 + 1] = -__expf(al.y);
        a[j * 4 + 2] = -__expf(al.z); a[j * 4 + 3] = -__expf(al.w);
    }
    float H[16];
#pragma unroll
    for (int n = 0; n < 16; n++) H[n] = 0.f;

    for (int c = 0; c < NCH; c++) {
        float* hp = Hc + ((size_t)c * 4096 + bd) * 16;
        float sdv = sumdv[c * 4096 + bd];
        float hc[16];
#pragma unroll
        for (int j = 0; j < 4; j++) {
            float4 q = *(const float4*)(hp + j * 4);
            hc[j * 4 + 0] = q.x; hc[j * 4 + 1] = q.y; hc[j * 4 + 2] = q.z; hc[j * 4 + 3] = q.w;
        }
#pragma unroll
        for (int j = 0; j < 4; j++)
            *(float4*)(hp + j * 4) = make_float4(H[j * 4], H[j * 4 + 1], H[j * 4 + 2], H[j * 4 + 3]);
#pragma unroll
        for (int n = 0; n < 16; n++)
            H[n] = __expf(a[n] * sdv) * H[n] + hc[n];
    }
}

// ---------------------------------------------------------------------------
// Scan phase C
// ---------------------------------------------------------------------------
__global__ __launch_bounds__(256) void scan_c(
    const float* __restrict__ delta, const float* __restrict__ u,
    const float* __restrict__ xdbl, const float* __restrict__ A_log,
    const float* __restrict__ Dv, const float* __restrict__ Hstart,
    unsigned short* __restrict__ y)
{
    int gid = blockIdx.x * 256 + threadIdx.x;
    int c = gid >> 12;
    int bd = gid & 4095;
    int b = bd >> 10, d = bd & 1023;

    float a[16];
#pragma unroll
    for (int j = 0; j < 4; j++) {
        float4 al = *(const float4*)(A_log + d * 16 + j * 4);
        a[j * 4 + 0] = -__expf(al.x); a[j * 4 + 1] = -__expf(al.y);
        a[j * 4 + 2] = -__expf(al.z); a[j * 4 + 3] = -__expf(al.w);
    }
    float h[16];
    const float* hp = Hstart + ((size_t)c * 4096 + bd) * 16;
#pragma unroll
    for (int j = 0; j < 4; j++) {
        float4 q = *(const float4*)(hp + j * 4);
        h[j * 4 + 0] = q.x; h[j * 4 + 1] = q.y; h[j * 4 + 2] = q.z; h[j * 4 + 3] = q.w;
    }
    float Dd = Dv[d];

    int t0 = c * CHL;
    const float* dp = delta + ((size_t)(b * L_) + t0) * DI + d;
    const float* up = u + ((size_t)(b * L_) + t0) * DI + d;
    const float* xp = xdbl + ((size_t)(b * L_) + t0) * 128;
    unsigned short* yp = y + ((size_t)(b * L_) + t0) * DI + d;

#pragma unroll 4
    for (int t = 0; t < CHL; t++) {
        float dv = dp[t * DI];
        float uv = up[t * DI];
        float duv = dv * uv;
        float Bv[16], Cv[16];
#pragma unroll
        for (int j = 0; j < 4; j++) {
            float4 bq = *(const float4*)(xp + t * 128 + 64 + j * 4);
            Bv[j * 4 + 0] = bq.x; Bv[j * 4 + 1] = bq.y;
            Bv[j * 4 + 2] = bq.z; Bv[j * 4 + 3] = bq.w;
            float4 cq = *(const float4*)(xp + t * 128 + 80 + j * 4);
            Cv[j * 4 + 0] = cq.x; Cv[j * 4 + 1] = cq.y;
            Cv[j * 4 + 2] = cq.z; Cv[j * 4 + 3] = cq.w;
        }
        float ys = 0.f;
#pragma unroll
        for (int n = 0; n < 16; n++) {
            h[n] = __expf(dv * a[n]) * h[n] + duv * Bv[n];
            ys += h[n] * Cv[n];
        }
        yp[t * DI] = f2bf(ys + uv * Dd);
    }
}

// ---------------------------------------------------------------------------
// V [4096][1024] -> VT [bh][256][1024] (bf16 tiled transpose)
// ---------------------------------------------------------------------------
__global__ __launch_bounds__(256) void transpose_v(
    const unsigned short* __restrict__ V, unsigned short* __restrict__ VT)
{
    __shared__ unsigned short tl[32][36];
    int bh = blockIdx.z;
    int b = bh >> 2, h = bh & 3;
    int l0 = blockIdx.x * 32, d0 = blockIdx.y * 32;
    int tid = threadIdx.x;
    int r = tid >> 3, c4 = (tid & 7) * 4;

    const unsigned short* src = V + ((size_t)(b * L_ + l0 + r)) * 1024 + h * DK + d0 + c4;
    ushort4 v = *(const ushort4*)src;
    tl[r][c4 + 0] = v.x; tl[r][c4 + 1] = v.y; tl[r][c4 + 2] = v.z; tl[r][c4 + 3] = v.w;
    __syncthreads();

    unsigned short* dst = VT + ((size_t)bh * DK + d0 + r) * L_ + l0 + c4;
    ushort4 o;
    o.x = tl[c4 + 0][r]; o.y = tl[c4 + 1][r]; o.z = tl[c4 + 2][r]; o.w = tl[c4 + 3][r];
    *(ushort4*)dst = o;
}

// ---------------------------------------------------------------------------
extern "C" void kernel_launch(void* const* d_in, const int* in_sizes, int n_in,
                              void* d_out, int out_size, void* d_ws, size_t ws_size,
                              hipStream_t stream)
{
    const float* x         = (const float*)d_in[0];
    const float* xx        = (const float*)d_in[1];
    const float* in_proj_w = (const float*)d_in[2];
    const float* conv_w    = (const float*)d_in[3];
    const float* conv_b    = (const float*)d_in[4];
    const float* x_proj_w  = (const float*)d_in[5];
    const float* dt_proj_w = (const float*)d_in[6];
    const float* dt_proj_b = (const float*)d_in[7];
    const float* A_log     = (const float*)d_in[8];
    const float* Dvec      = (const float*)d_in[9];
    const float* wq        = (const float*)d_in[10];
    const float* bq        = (const float*)d_in[11];
    const float* wk        = (const float*)d_in[12];
    const float* bk        = (const float*)d_in[13];
    const float* wv        = (const float*)d_in[14];
    const float* bv        = (const float*)d_in[15];
    const float* wo        = (const float*)d_in[16];
    const float* bo        = (const float*)d_in[17];
    float* out = (float*)d_out;

    char* w = (char*)d_ws;
    const size_t MB = 1024 * 1024, KB = 1024;
    float*          u_f    = (float*)(w + 0);                // 16 MB, dead after scan
    float*          delta  = (float*)(w + 16 * MB);          // 16 MB, dead after scan
    float*          Opart  = (float*)(w + 0);                // 32 MB (aliases u_f+delta)
    unsigned short* x_bf   = (unsigned short*)(w + 32 * MB); // 8 MB -> Q_bf
    unsigned short* Q_bf   = x_bf;
    unsigned short* q_bf   = (unsigned short*)(w + 40 * MB); // 8 MB -> VT
    unsigned short* VT     = q_bf;
    unsigned short* y_bf   = (unsigned short*)(w + 48 * MB); // 8 MB -> AO
    unsigned short* AO     = y_bf;
    unsigned short* K_bf   = (unsigned short*)(w + 56 * MB); // 8 MB
    unsigned short* V_bf   = (unsigned short*)(w + 64 * MB); // 8 MB
    unsigned short* u_bf   = (unsigned short*)(w + 72 * MB); // 8 MB -> Hc
    float*          Hc     = (float*)(w + 72 * MB);
    float*          xdbl   = (float*)(w + 80 * MB);          // 2 MB
    unsigned short* xdblb  = (unsigned short*)(w + 82 * MB); // 1 MB
    unsigned short* w_in   = (unsigned short*)(w + 83 * MB); // 2 MB
    unsigned short* w_q    = (unsigned short*)(w + 85 * MB); // 2 MB
    unsigned short* w_k    = (unsigned short*)(w + 87 * MB); // 2 MB
    unsigned short* w_v    = (unsigned short*)(w + 89 * MB); // 2 MB
    unsigned short* w_o    = (unsigned short*)(w + 91 * MB); // 2 MB
    unsigned short* w_xp   = (unsigned short*)(w + 93 * MB);            // 256 KB
    unsigned short* w_dt   = (unsigned short*)(w + 93 * MB + 256 * KB); // 128 KB
    float*          sumdv  = (float*)(w + 93 * MB + 384 * KB);          // 512 KB
    float*          mbuf   = (float*)(w + 94 * MB);                     // 128 KB
    float*          lbuf   = (float*)(w + 94 * MB + 256 * KB);          // 128 KB

    dim3 blk(256);

    // 1. fused casts
    CastArgs ca;
    ca.s[0] = x;         ca.d[0] = x_bf;  ca.n[0] = 4194304; ca.ns[0] = 4194304;
    ca.s[1] = in_proj_w; ca.d[1] = w_in;  ca.n[1] = 1048576; ca.ns[1] = 1048576;
    ca.s[2] = wq;        ca.d[2] = w_q;   ca.n[2] = 1048576; ca.ns[2] = 1048576;
    ca.s[3] = wk;        ca.d[3] = w_k;   ca.n[3] = 1048576; ca.ns[3] = 1048576;
    ca.s[4] = wv;        ca.d[4] = w_v;   ca.n[4] = 1048576; ca.ns[4] = 1048576;
    ca.s[5] = wo;        ca.d[5] = w_o;   ca.n[5] = 1048576; ca.ns[5] = 1048576;
    ca.s[6] = x_proj_w;  ca.d[6] = w_xp;  ca.n[6] = 131072;  ca.ns[6] = 98304;
    ca.s[7] = dt_proj_w; ca.d[7] = w_dt;  ca.n[7] = 65536;   ca.ns[7] = 65536;
    cast_multi<<<dim3(4096, 8), blk, 0, stream>>>(ca);

    // 2. conv + silu
    conv_silu_kernel<<<dim3(16384), blk, 0, stream>>>(xx, conv_w, conv_b, u_f, u_bf);

    // 3. in_proj || x_proj
    {
        GArgs ga = {};
        ga.g[0] = (GDesc){x_bf, w_in, nullptr, nullptr, q_bf,
                          1024, 1024, 1024, 1024, 0, 1, 1.0f, 8, 32};
        ga.g[1] = (GDesc){u_bf, w_xp, nullptr, xdbl, xdblb,
                          1024, 1024, 1024, 128, 128, 2, 1.0f, 1, 32};
        gemm_multi<<<dim3(8, 32, 2), blk, 0, stream>>>(ga);
    }
    // 4. dt_proj (softplus)
    {
        GArgs ga = {};
        ga.g[0] = (GDesc){xdblb, w_dt, dt_proj_b, delta, nullptr,
                          64, 128, 64, 1024, 0, 0 | 4, 1.0f, 8, 32};
        gemm_multi<<<dim3(8, 32, 1), blk, 0, stream>>>(ga);
    }
    // 5-7. chunked scan
    scan_a<<<dim3(512), blk, 0, stream>>>(delta, u_f, xdbl, A_log, Hc, sumdv);
    scan_b<<<dim3(16), blk, 0, stream>>>(Hc, sumdv, A_log);
    scan_c<<<dim3(512), blk, 0, stream>>>(delta, u_f, xdbl, A_log, Dvec, Hc, y_bf);

    // 8. Q || K || V projections
    {
        GArgs ga = {};
        ga.g[0] = (GDesc){q_bf, w_q, bq, nullptr, Q_bf, 1024, 1024, 1024, 1024, 0, 1, 1.0f, 8, 32};
        ga.g[1] = (GDesc){y_bf, w_k, bk, nullptr, K_bf, 1024, 1024, 1024, 1024, 0, 1, 1.0f, 8, 32};
        ga.g[2] = (GDesc){y_bf, w_v, bv, nullptr, V_bf, 1024, 1024, 1024, 1024, 0, 1, 1.0f, 8, 32};
        gemm_multi<<<dim3(8, 32, 3), blk, 0, stream>>>(ga);
    }
    // 9. V transpose (VT overwrites q_bf, consumed by Q projection)
    transpose_v<<<dim3(32, 8, 16), blk, 0, stream>>>(V_bf, VT);
    // 10. flash attention split-K2, barrier-free -> Opart/m/l (Opart aliases u/delta)
    flash_attn<<<dim3(512), blk, 0, stream>>>(Q_bf, K_bf, VT, Opart, mbuf, lbuf);
    // 11. merge partials -> AO (overwrites y_bf, consumed by K/V projections)
    attn_merge<<<dim3(4096), blk, 0, stream>>>(Opart, mbuf, lbuf, AO);
    // 12. out = AO @ wo^T + bo (fp32)
    {
        GArgs ga = {};
        ga.g[0] = (GDesc){AO, w_o, bo, out, nullptr, 1024, 1024, 1024, 1024, 0, 0, 1.0f, 8, 32};
        gemm_multi<<<dim3(8, 32, 1), blk, 0, stream>>>(ga);
    }
}

// Round 8
// 438.503 us; speedup vs baseline: 1.1567x; 1.1567x over previous
//
#include <hip/hip_runtime.h>
#include <math.h>

#define B_  4
#define L_  1024
#define DM  1024
#define DI  1024
#define DS  16
#define DR  64
#define DCV 4
#define NH  4
#define DK  256

#define NCH 32         // scan time-chunks
#define CHL (L_ / NCH) // 32 steps per chunk

typedef __attribute__((ext_vector_type(8))) short short8;
typedef __attribute__((ext_vector_type(4))) float floatx4;

static __device__ __forceinline__ unsigned short f2bf(float f) {
    unsigned int u = __float_as_uint(f);
    u += 0x7fffu + ((u >> 16) & 1u);
    return (unsigned short)(u >> 16);
}
static __device__ __forceinline__ float bf2f(unsigned short s) {
    return __uint_as_float(((unsigned int)s) << 16);
}

// ---------------------------------------------------------------------------
// prep: fused conv+silu (region 0) and all fp32->bf16 casts, one dispatch.
// Flat 1D grid, 25792 blocks:
//   [0,16384)        conv+silu -> u_f (fp32) + u_bf
//   [16384,20480)    cast x -> x_bf
//   then 7 weight regions (1024,1024,1024,1024,1024,128,64 blocks)
// ---------------------------------------------------------------------------
struct PrepArgs {
    const float* xx; const float* cw; const float* cb;
    float* u; unsigned short* ub;
    const float* xs; unsigned short* xd;
    const float* s[7]; unsigned short* d[7];
    int n[7];   // dest elements (mult of 1024)
    int ns[7];  // source elements (<= n, zero-pad past)
};

__global__ __launch_bounds__(256) void prep(PrepArgs pa)
{
    int bid = blockIdx.x, tid = threadIdx.x;
    if (bid < 16384) {
        // conv + silu
        int idx = bid * 256 + tid;
        int d = idx & (DI - 1);
        int l = (idx >> 10) & (L_ - 1);
        int b = idx >> 20;
        const float* xb = pa.xx + (size_t)b * L_ * DI + d;
        float z = pa.cb[d];
#pragma unroll
        for (int j = 0; j < DCV; j++) {
            int t = l - (DCV - 1) + j;
            if (t >= 0) z += xb[(size_t)t * DI] * pa.cw[d * DCV + j];
        }
        float v = z / (1.0f + __expf(-z));
        pa.u[idx] = v;
        pa.ub[idx] = f2bf(v);
        return;
    }
    bid -= 16384;
    if (bid < 4096) {
        int i = (bid * 256 + tid) * 4;
        float4 v = *(const float4*)(pa.xs + i);
        ushort4 o;
        o.x = f2bf(v.x); o.y = f2bf(v.y); o.z = f2bf(v.z); o.w = f2bf(v.w);
        *(ushort4*)(pa.xd + i) = o;
        return;
    }
    bid -= 4096;
#pragma unroll
    for (int r = 0; r < 7; r++) {
        int nb = pa.n[r] >> 10;
        if (bid < nb) {
            int i = (bid * 256 + tid) * 4;
            int ns = pa.ns[r];
            const float* s = pa.s[r];
            ushort4 o;
            if (i + 4 <= ns) {
                float4 v = *(const float4*)(s + i);
                o.x = f2bf(v.x); o.y = f2bf(v.y); o.z = f2bf(v.z); o.w = f2bf(v.w);
            } else {
                float v[4];
#pragma unroll
                for (int j = 0; j < 4; j++) v[j] = (i + j < ns) ? s[i + j] : 0.f;
                o.x = f2bf(v[0]); o.y = f2bf(v[1]); o.z = f2bf(v[2]); o.w = f2bf(v[3]);
            }
            *(ushort4*)(pa.d[r] + i) = o;
            return;
        }
        bid -= nb;
    }
}

// ---------------------------------------------------------------------------
// Multi-descriptor bf16 MFMA GEMM: per z, C = act(A @ W^T * scale + bias)
// mode & 3: 0 = fp32 out, 1 = bf16 out, 2 = both. mode & 4: softplus.
// ---------------------------------------------------------------------------
struct GDesc {
    const unsigned short* A;
    const unsigned short* W;
    const float* bias;
    float* Cf;
    unsigned short* Cb;
    int K, lda, ldw, ldc, ldc2;
    int mode;
    float scale;
    int gx, gy;
};
struct GArgs { GDesc g[3]; };

__global__ __launch_bounds__(256) void gemm_multi(GArgs ga)
{
    GDesc g = ga.g[blockIdx.z];
    if ((int)blockIdx.x >= g.gx || (int)blockIdx.y >= g.gy) return;

    __shared__ __align__(16) unsigned short Asm[128 * 32];
    __shared__ __align__(16) unsigned short Bsm[128 * 32];

    int tid = threadIdx.x;
    int wid = tid >> 6;
    int lane = tid & 63;
    int wm = wid & 1, wn = wid >> 1;
    int lr = lane & 15, quad = lane >> 4;

    const unsigned short* Ab = g.A + (size_t)blockIdx.y * 128 * g.lda;
    const unsigned short* Wb = g.W + (size_t)blockIdx.x * 128 * g.ldw;

    int srow = tid >> 2;
    int scol = (tid & 3) * 8;
    const unsigned short* Ap = Ab + (size_t)srow * g.lda + scol;
    const unsigned short* Wp = Wb + (size_t)srow * g.ldw + scol;

    unsigned short* lA0 = &Asm[(wid * 16) * 32];
    unsigned short* lA1 = &Asm[(64 + wid * 16) * 32];
    unsigned short* lB0 = &Bsm[(wid * 16) * 32];
    unsigned short* lB1 = &Bsm[(64 + wid * 16) * 32];

    floatx4 acc[4][4];
#pragma unroll
    for (int i = 0; i < 4; i++)
#pragma unroll
        for (int j = 0; j < 4; j++) acc[i][j] = (floatx4){0.f, 0.f, 0.f, 0.f};

#define GLL(gp, lp) __builtin_amdgcn_global_load_lds( \
        (const __attribute__((address_space(1))) void*)(gp), \
        (__attribute__((address_space(3))) void*)(lp), 16, 0, 0)

    for (int k0 = 0; k0 < g.K; k0 += 32) {
        GLL(Ap, lA0);
        GLL(Ap + (size_t)64 * g.lda, lA1);
        GLL(Wp, lB0);
        GLL(Wp + (size_t)64 * g.ldw, lB1);
        Ap += 32; Wp += 32;
        __syncthreads();

        short8 af[4], bf[4];
#pragma unroll
        for (int mt = 0; mt < 4; mt++)
            af[mt] = *(const short8*)&Asm[(wm * 64 + mt * 16 + lr) * 32 + quad * 8];
#pragma unroll
        for (int nt = 0; nt < 4; nt++)
            bf[nt] = *(const short8*)&Bsm[(wn * 64 + nt * 16 + lr) * 32 + quad * 8];
#pragma unroll
        for (int mt = 0; mt < 4; mt++)
#pragma unroll
            for (int nt = 0; nt < 4; nt++)
                acc[mt][nt] = __builtin_amdgcn_mfma_f32_16x16x32_bf16(
                    af[mt], bf[nt], acc[mt][nt], 0, 0, 0);
        __syncthreads();
    }
#undef GLL

    int bm = blockIdx.y * 128, bn = blockIdx.x * 128;
    int m = g.mode & 3;
#pragma unroll
    for (int mt = 0; mt < 4; mt++) {
#pragma unroll
        for (int nt = 0; nt < 4; nt++) {
            int row0 = bm + wm * 64 + mt * 16 + quad * 4;
            int col = bn + wn * 64 + nt * 16 + lr;
            float bv = g.bias ? g.bias[col] : 0.f;
#pragma unroll
            for (int i = 0; i < 4; i++) {
                float v = acc[mt][nt][i] * g.scale + bv;
                if (g.mode & 4) v = (v > 15.f) ? v : log1pf(__expf(v));
                if (m == 0) {
                    g.Cf[(size_t)(row0 + i) * g.ldc + col] = v;
                } else if (m == 1) {
                    g.Cb[(size_t)(row0 + i) * g.ldc + col] = f2bf(v);
                } else {
                    g.Cf[(size_t)(row0 + i) * g.ldc + col] = v;
                    g.Cb[(size_t)(row0 + i) * g.ldc2 + col] = f2bf(v);
                }
            }
        }
    }
}

// ---------------------------------------------------------------------------
// Batched-strided bf16 MFMA GEMM (attention): z -> b=z>>2, h=z&3
// ---------------------------------------------------------------------------
__global__ __launch_bounds__(256) void gemm_batched(
    const unsigned short* __restrict__ A, const unsigned short* __restrict__ W,
    unsigned short* __restrict__ C,
    int K, int lda, int ldw, int ldc,
    long long sA1, long long sA2, long long sW1, long long sW2,
    long long sC1, long long sC2, float scale)
{
    __shared__ __align__(16) unsigned short Asm[128 * 32];
    __shared__ __align__(16) unsigned short Bsm[128 * 32];

    int z = blockIdx.z;
    long long bq = z >> 2, hq = z & 3;
    int tid = threadIdx.x;
    int wid = tid >> 6;
    int lane = tid & 63;
    int wm = wid & 1, wn = wid >> 1;
    int lr = lane & 15, quad = lane >> 4;

    const unsigned short* Ab = A + bq * sA1 + hq * sA2 + (size_t)blockIdx.y * 128 * lda;
    const unsigned short* Wb = W + bq * sW1 + hq * sW2 + (size_t)blockIdx.x * 128 * ldw;

    int srow = tid >> 2;
    int scol = (tid & 3) * 8;
    const unsigned short* Ap = Ab + (size_t)srow * lda + scol;
    const unsigned short* Wp = Wb + (size_t)srow * ldw + scol;

    unsigned short* lA0 = &Asm[(wid * 16) * 32];
    unsigned short* lA1 = &Asm[(64 + wid * 16) * 32];
    unsigned short* lB0 = &Bsm[(wid * 16) * 32];
    unsigned short* lB1 = &Bsm[(64 + wid * 16) * 32];

    floatx4 acc[4][4];
#pragma unroll
    for (int i = 0; i < 4; i++)
#pragma unroll
        for (int j = 0; j < 4; j++) acc[i][j] = (floatx4){0.f, 0.f, 0.f, 0.f};

#define GLL(gp, lp) __builtin_amdgcn_global_load_lds( \
        (const __attribute__((address_space(1))) void*)(gp), \
        (__attribute__((address_space(3))) void*)(lp), 16, 0, 0)

    for (int k0 = 0; k0 < K; k0 += 32) {
        GLL(Ap, lA0);
        GLL(Ap + (size_t)64 * lda, lA1);
        GLL(Wp, lB0);
        GLL(Wp + (size_t)64 * ldw, lB1);
        Ap += 32; Wp += 32;
        __syncthreads();

        short8 af[4], bf[4];
#pragma unroll
        for (int mt = 0; mt < 4; mt++)
            af[mt] = *(const short8*)&Asm[(wm * 64 + mt * 16 + lr) * 32 + quad * 8];
#pragma unroll
        for (int nt = 0; nt < 4; nt++)
            bf[nt] = *(const short8*)&Bsm[(wn * 64 + nt * 16 + lr) * 32 + quad * 8];
#pragma unroll
        for (int mt = 0; mt < 4; mt++)
#pragma unroll
            for (int nt = 0; nt < 4; nt++)
                acc[mt][nt] = __builtin_amdgcn_mfma_f32_16x16x32_bf16(
                    af[mt], bf[nt], acc[mt][nt], 0, 0, 0);
        __syncthreads();
    }
#undef GLL

    long long coff = bq * sC1 + hq * sC2;
    int bm = blockIdx.y * 128, bn = blockIdx.x * 128;
    unsigned short* Cb = C + coff;

#pragma unroll
    for (int mt = 0; mt < 4; mt++) {
#pragma unroll
        for (int nt = 0; nt < 4; nt++) {
            int row0 = bm + wm * 64 + mt * 16 + quad * 4;
            int col = bn + wn * 64 + nt * 16 + lr;
#pragma unroll
            for (int i = 0; i < 4; i++)
                Cb[(size_t)(row0 + i) * ldc + col] = f2bf(acc[mt][nt][i] * scale);
        }
    }
}

// ---------------------------------------------------------------------------
// Scan phase A: one thread = (b,d,chunk), 16 states in registers.
// ---------------------------------------------------------------------------
__global__ __launch_bounds__(256) void scan_a(
    const float* __restrict__ delta, const float* __restrict__ u,
    const float* __restrict__ xdbl, const float* __restrict__ A_log,
    float* __restrict__ Hc, float* __restrict__ sumdv)
{
    int gid = blockIdx.x * 256 + threadIdx.x;
    int c = gid >> 12;
    int bd = gid & 4095;
    int b = bd >> 10, d = bd & 1023;

    float a[16];
#pragma unroll
    for (int j = 0; j < 4; j++) {
        float4 al = *(const float4*)(A_log + d * 16 + j * 4);
        a[j * 4 + 0] = -__expf(al.x); a[j * 4 + 1] = -__expf(al.y);
        a[j * 4 + 2] = -__expf(al.z); a[j * 4 + 3] = -__expf(al.w);
    }
    float h[16];
#pragma unroll
    for (int n = 0; n < 16; n++) h[n] = 0.f;
    float sd = 0.f;

    int t0 = c * CHL;
    const float* dp = delta + ((size_t)(b * L_) + t0) * DI + d;
    const float* up = u + ((size_t)(b * L_) + t0) * DI + d;
    const float* xp = xdbl + ((size_t)(b * L_) + t0) * 128;

#pragma unroll 4
    for (int t = 0; t < CHL; t++) {
        float dv = dp[t * DI];
        float uv = up[t * DI];
        float duv = dv * uv;
        sd += dv;
        float Bv[16];
#pragma unroll
        for (int j = 0; j < 4; j++) {
            float4 bq = *(const float4*)(xp + t * 128 + 64 + j * 4);
            Bv[j * 4 + 0] = bq.x; Bv[j * 4 + 1] = bq.y;
            Bv[j * 4 + 2] = bq.z; Bv[j * 4 + 3] = bq.w;
        }
#pragma unroll
        for (int n = 0; n < 16; n++)
            h[n] = __expf(dv * a[n]) * h[n] + duv * Bv[n];
    }

    float* hp = Hc + ((size_t)c * 4096 + bd) * 16;
#pragma unroll
    for (int j = 0; j < 4; j++)
        *(float4*)(hp + j * 4) = make_float4(h[j * 4], h[j * 4 + 1], h[j * 4 + 2], h[j * 4 + 3]);
    sumdv[c * 4096 + bd] = sd;
}

// ---------------------------------------------------------------------------
// Scan phase B: in-place combine — Hc[c][bd][*] becomes chunk START state
// ---------------------------------------------------------------------------
__global__ __launch_bounds__(256) void scan_b(
    float* __restrict__ Hc, const float* __restrict__ sumdv,
    const float* __restrict__ A_log)
{
    int bd = blockIdx.x * 256 + threadIdx.x;
    int d = bd & 1023;

    float a[16];
#pragma unroll
    for (int j = 0; j < 4; j++) {
        float4 al = *(const float4*)(A_log + d * 16 + j * 4);
        a[j * 4 + 0] = -__expf(al.x); a[j * 4 + 1] = -__expf(al.y);
        a[j * 4 + 2] = -__expf(al.z); a[j * 4 + 3] = -__expf(al.w);
    }
    float H[16];
#pragma unroll
    for (int n = 0; n < 16; n++) H[n] = 0.f;

    for (int c = 0; c < NCH; c++) {
        float* hp = Hc + ((size_t)c * 4096 + bd) * 16;
        float sdv = sumdv[c * 4096 + bd];
        float hc[16];
#pragma unroll
        for (int j = 0; j < 4; j++) {
            float4 q = *(const float4*)(hp + j * 4);
            hc[j * 4 + 0] = q.x; hc[j * 4 + 1] = q.y; hc[j * 4 + 2] = q.z; hc[j * 4 + 3] = q.w;
        }
#pragma unroll
        for (int j = 0; j < 4; j++)
            *(float4*)(hp + j * 4) = make_float4(H[j * 4], H[j * 4 + 1], H[j * 4 + 2], H[j * 4 + 3]);
#pragma unroll
        for (int n = 0; n < 16; n++)
            H[n] = __expf(a[n] * sdv) * H[n] + hc[n];
    }
}

// ---------------------------------------------------------------------------
// Scan phase C: re-run chunk from start state, emit y (bf16)
// ---------------------------------------------------------------------------
__global__ __launch_bounds__(256) void scan_c(
    const float* __restrict__ delta, const float* __restrict__ u,
    const float* __restrict__ xdbl, const float* __restrict__ A_log,
    const float* __restrict__ Dv, const float* __restrict__ Hstart,
    unsigned short* __restrict__ y)
{
    int gid = blockIdx.x * 256 + threadIdx.x;
    int c = gid >> 12;
    int bd = gid & 4095;
    int b = bd >> 10, d = bd & 1023;

    float a[16];
#pragma unroll
    for (int j = 0; j < 4; j++) {
        float4 al = *(const float4*)(A_log + d * 16 + j * 4);
        a[j * 4 + 0] = -__expf(al.x); a[j * 4 + 1] = -__expf(al.y);
        a[j * 4 + 2] = -__expf(al.z); a[j * 4 + 3] = -__expf(al.w);
    }
    float h[16];
    const float* hp = Hstart + ((size_t)c * 4096 + bd) * 16;
#pragma unroll
    for (int j = 0; j < 4; j++) {
        float4 q = *(const float4*)(hp + j * 4);
        h[j * 4 + 0] = q.x; h[j * 4 + 1] = q.y; h[j * 4 + 2] = q.z; h[j * 4 + 3] = q.w;
    }
    float Dd = Dv[d];

    int t0 = c * CHL;
    const float* dp = delta + ((size_t)(b * L_) + t0) * DI + d;
    const float* up = u + ((size_t)(b * L_) + t0) * DI + d;
    const float* xp = xdbl + ((size_t)(b * L_) + t0) * 128;
    unsigned short* yp = y + ((size_t)(b * L_) + t0) * DI + d;

#pragma unroll 4
    for (int t = 0; t < CHL; t++) {
        float dv = dp[t * DI];
        float uv = up[t * DI];
        float duv = dv * uv;
        float Bv[16], Cv[16];
#pragma unroll
        for (int j = 0; j < 4; j++) {
            float4 bq = *(const float4*)(xp + t * 128 + 64 + j * 4);
            Bv[j * 4 + 0] = bq.x; Bv[j * 4 + 1] = bq.y;
            Bv[j * 4 + 2] = bq.z; Bv[j * 4 + 3] = bq.w;
            float4 cq = *(const float4*)(xp + t * 128 + 80 + j * 4);
            Cv[j * 4 + 0] = cq.x; Cv[j * 4 + 1] = cq.y;
            Cv[j * 4 + 2] = cq.z; Cv[j * 4 + 3] = cq.w;
        }
        float ys = 0.f;
#pragma unroll
        for (int n = 0; n < 16; n++) {
            h[n] = __expf(dv * a[n]) * h[n] + duv * Bv[n];
            ys += h[n] * Cv[n];
        }
        yp[t * DI] = f2bf(ys + uv * Dd);
    }
}

// ---------------------------------------------------------------------------
// Row softmax over S [16384 rows][1024 cols] bf16, in place.
// ---------------------------------------------------------------------------
__global__ __launch_bounds__(256) void softmax_rows(unsigned short* __restrict__ S)
{
    int row = blockIdx.x * 4 + (threadIdx.x >> 6);
    int lane = threadIdx.x & 63;
    unsigned short* p = S + (size_t)row * 1024;

    float v[16];
#pragma unroll
    for (int ch = 0; ch < 4; ch++) {
        ushort4 u4 = *(const ushort4*)(p + ch * 256 + lane * 4);
        v[ch * 4 + 0] = bf2f(u4.x); v[ch * 4 + 1] = bf2f(u4.y);
        v[ch * 4 + 2] = bf2f(u4.z); v[ch * 4 + 3] = bf2f(u4.w);
    }
    float m = -1e30f;
#pragma unroll
    for (int i = 0; i < 16; i++) m = fmaxf(m, v[i]);
#pragma unroll
    for (int off = 32; off >= 1; off >>= 1) m = fmaxf(m, __shfl_xor(m, off));
    float s = 0.f;
#pragma unroll
    for (int i = 0; i < 16; i++) { v[i] = __expf(v[i] - m); s += v[i]; }
#pragma unroll
    for (int off = 32; off >= 1; off >>= 1) s += __shfl_xor(s, off);
    float inv = 1.0f / s;
#pragma unroll
    for (int ch = 0; ch < 4; ch++) {
        ushort4 o;
        o.x = f2bf(v[ch * 4 + 0] * inv); o.y = f2bf(v[ch * 4 + 1] * inv);
        o.z = f2bf(v[ch * 4 + 2] * inv); o.w = f2bf(v[ch * 4 + 3] * inv);
        *(ushort4*)(p + ch * 256 + lane * 4) = o;
    }
}

// ---------------------------------------------------------------------------
// V [4096][1024] -> VT [bh][256][1024] (bf16 tiled transpose)
// ---------------------------------------------------------------------------
__global__ __launch_bounds__(256) void transpose_v(
    const unsigned short* __restrict__ V, unsigned short* __restrict__ VT)
{
    __shared__ unsigned short tl[32][36];
    int bh = blockIdx.z;
    int b = bh >> 2, h = bh & 3;
    int l0 = blockIdx.x * 32, d0 = blockIdx.y * 32;
    int tid = threadIdx.x;
    int r = tid >> 3, c4 = (tid & 7) * 4;

    const unsigned short* src = V + ((size_t)(b * L_ + l0 + r)) * 1024 + h * DK + d0 + c4;
    ushort4 v = *(const ushort4*)src;
    tl[r][c4 + 0] = v.x; tl[r][c4 + 1] = v.y; tl[r][c4 + 2] = v.z; tl[r][c4 + 3] = v.w;
    __syncthreads();

    unsigned short* dst = VT + ((size_t)bh * DK + d0 + r) * L_ + l0 + c4;
    ushort4 o;
    o.x = tl[c4 + 0][r]; o.y = tl[c4 + 1][r]; o.z = tl[c4 + 2][r]; o.w = tl[c4 + 3][r];
    *(ushort4*)dst = o;
}

// ---------------------------------------------------------------------------
extern "C" void kernel_launch(void* const* d_in, const int* in_sizes, int n_in,
                              void* d_out, int out_size, void* d_ws, size_t ws_size,
                              hipStream_t stream)
{
    const float* x         = (const float*)d_in[0];
    const float* xx        = (const float*)d_in[1];
    const float* in_proj_w = (const float*)d_in[2];
    const float* conv_w    = (const float*)d_in[3];
    const float* conv_b    = (const float*)d_in[4];
    const float* x_proj_w  = (const float*)d_in[5];
    const float* dt_proj_w = (const float*)d_in[6];
    const float* dt_proj_b = (const float*)d_in[7];
    const float* A_log     = (const float*)d_in[8];
    const float* Dvec      = (const float*)d_in[9];
    const float* wq        = (const float*)d_in[10];
    const float* bq        = (const float*)d_in[11];
    const float* wk        = (const float*)d_in[12];
    const float* bk        = (const float*)d_in[13];
    const float* wv        = (const float*)d_in[14];
    const float* bv        = (const float*)d_in[15];
    const float* wo        = (const float*)d_in[16];
    const float* bo        = (const float*)d_in[17];
    float* out = (float*)d_out;

    char* w = (char*)d_ws;
    const size_t MB = 1024 * 1024, KB = 1024;
    float*          u_f    = (float*)(w + 0);                // 16 MB, dead after scan
    float*          delta  = (float*)(w + 16 * MB);          // 16 MB, dead after scan
    unsigned short* Sbuf   = (unsigned short*)(w + 0);       // 32 MB (aliases u_f+delta)
    unsigned short* x_bf   = (unsigned short*)(w + 32 * MB); // 8 MB -> Q_bf
    unsigned short* Q_bf   = x_bf;
    unsigned short* q_bf   = (unsigned short*)(w + 40 * MB); // 8 MB -> VT
    unsigned short* VT     = q_bf;
    unsigned short* y_bf   = (unsigned short*)(w + 48 * MB); // 8 MB -> AO
    unsigned short* AO     = y_bf;
    unsigned short* K_bf   = (unsigned short*)(w + 56 * MB); // 8 MB
    unsigned short* V_bf   = (unsigned short*)(w + 64 * MB); // 8 MB
    unsigned short* u_bf   = (unsigned short*)(w + 72 * MB); // 8 MB -> Hc
    float*          Hc     = (float*)(w + 72 * MB);
    float*          xdbl   = (float*)(w + 80 * MB);          // 2 MB
    unsigned short* xdblb  = (unsigned short*)(w + 82 * MB); // 1 MB
    unsigned short* w_in   = (unsigned short*)(w + 83 * MB); // 2 MB
    unsigned short* w_q    = (unsigned short*)(w + 85 * MB); // 2 MB
    unsigned short* w_k    = (unsigned short*)(w + 87 * MB); // 2 MB
    unsigned short* w_v    = (unsigned short*)(w + 89 * MB); // 2 MB
    unsigned short* w_o    = (unsigned short*)(w + 91 * MB); // 2 MB
    unsigned short* w_xp   = (unsigned short*)(w + 93 * MB);            // 256 KB
    unsigned short* w_dt   = (unsigned short*)(w + 93 * MB + 256 * KB); // 128 KB
    float*          sumdv  = (float*)(w + 93 * MB + 384 * KB);          // 512 KB

    dim3 blk(256);
    const long long LL = L_;

    // 1. prep: conv+silu + all casts, one dispatch
    PrepArgs pa;
    pa.xx = xx; pa.cw = conv_w; pa.cb = conv_b; pa.u = u_f; pa.ub = u_bf;
    pa.xs = x; pa.xd = x_bf;
    pa.s[0] = in_proj_w; pa.d[0] = w_in; pa.n[0] = 1048576; pa.ns[0] = 1048576;
    pa.s[1] = wq;        pa.d[1] = w_q;  pa.n[1] = 1048576; pa.ns[1] = 1048576;
    pa.s[2] = wk;        pa.d[2] = w_k;  pa.n[2] = 1048576; pa.ns[2] = 1048576;
    pa.s[3] = wv;        pa.d[3] = w_v;  pa.n[3] = 1048576; pa.ns[3] = 1048576;
    pa.s[4] = wo;        pa.d[4] = w_o;  pa.n[4] = 1048576; pa.ns[4] = 1048576;
    pa.s[5] = x_proj_w;  pa.d[5] = w_xp; pa.n[5] = 131072;  pa.ns[5] = 98304;
    pa.s[6] = dt_proj_w; pa.d[6] = w_dt; pa.n[6] = 65536;   pa.ns[6] = 65536;
    prep<<<dim3(25792), blk, 0, stream>>>(pa);

    // 2. in_proj || x_proj
    {
        GArgs ga = {};
        ga.g[0] = (GDesc){x_bf, w_in, nullptr, nullptr, q_bf,
                          1024, 1024, 1024, 1024, 0, 1, 1.0f, 8, 32};
        ga.g[1] = (GDesc){u_bf, w_xp, nullptr, xdbl, xdblb,
                          1024, 1024, 1024, 128, 128, 2, 1.0f, 1, 32};
        gemm_multi<<<dim3(8, 32, 2), blk, 0, stream>>>(ga);
    }
    // 3. dt_proj (softplus)
    {
        GArgs ga = {};
        ga.g[0] = (GDesc){xdblb, w_dt, dt_proj_b, delta, nullptr,
                          64, 128, 64, 1024, 0, 0 | 4, 1.0f, 8, 32};
        gemm_multi<<<dim3(8, 32, 1), blk, 0, stream>>>(ga);
    }
    // 4-6. chunked scan
    scan_a<<<dim3(512), blk, 0, stream>>>(delta, u_f, xdbl, A_log, Hc, sumdv);
    scan_b<<<dim3(16), blk, 0, stream>>>(Hc, sumdv, A_log);
    scan_c<<<dim3(512), blk, 0, stream>>>(delta, u_f, xdbl, A_log, Dvec, Hc, y_bf);

    // 7. Q || K || V projections
    {
        GArgs ga = {};
        ga.g[0] = (GDesc){q_bf, w_q, bq, nullptr, Q_bf, 1024, 1024, 1024, 1024, 0, 1, 1.0f, 8, 32};
        ga.g[1] = (GDesc){y_bf, w_k, bk, nullptr, K_bf, 1024, 1024, 1024, 1024, 0, 1, 1.0f, 8, 32};
        ga.g[2] = (GDesc){y_bf, w_v, bv, nullptr, V_bf, 1024, 1024, 1024, 1024, 0, 1, 1.0f, 8, 32};
        gemm_multi<<<dim3(8, 32, 3), blk, 0, stream>>>(ga);
    }
    // 8. S = Q @ K^T * scale (batched; Sbuf aliases dead u_f/delta)
    gemm_batched<<<dim3(8, 8, 16), blk, 0, stream>>>(Q_bf, K_bf, Sbuf,
        DK, 1024, 1024, 1024,
        LL * 1024, 256, LL * 1024, 256,
        4 * LL * 1024, LL * 1024, 0.0625f);
    // 9. softmax
    softmax_rows<<<dim3(4096), blk, 0, stream>>>(Sbuf);
    // 10. V transpose (VT overwrites q_bf, consumed by Q projection)
    transpose_v<<<dim3(32, 8, 16), blk, 0, stream>>>(V_bf, VT);
    // 11. AO = P @ V
    gemm_batched<<<dim3(2, 8, 16), blk, 0, stream>>>(Sbuf, VT, AO,
        1024, 1024, 1024, 1024,
        4 * LL * 1024, LL * 1024,
        4 * (long long)DK * 1024, (long long)DK * 1024,
        LL * 1024, 256, 1.0f);
    // 12. out = AO @ wo^T + bo (fp32)
    {
        GArgs ga = {};
        ga.g[0] = (GDesc){AO, w_o, bo, out, nullptr, 1024, 1024, 1024, 1024, 0, 0, 1.0f, 8, 32};
        gemm_multi<<<dim3(8, 32, 1), blk, 0, stream>>>(ga);
    }
}